// Round 3
// baseline (236.542 us; speedup 1.0000x reference)
//
#include <hip/hip_runtime.h>
#include <hip/hip_bf16.h>
#include <stdint.h>

#define N_NODES 20000
#define N_EDGES 160000
#define DIN 512
#define DOUT 512
#define NBUCKET 11
#define KDIM 1024   // [h | feats]
#define BN_EPS 1e-5f
#define CAP 64         // fixed adjacency capacity; deg is Poisson(8), P(>=64) ~ 1e-40
#define CAST_BLOCKS (N_NODES / 4)                  // 5000 (4 rows / 256-thr block)
#define WT_BLOCKS ((KDIM / 32) * (DOUT / 32) * NBUCKET)  // 5632
#define BUCKET_BLOCKS ((N_NODES + 255) / 256)      // 79
#define GEMM_BLOCKS 192   // 12 groups x 16; tile=(b>>4)*8+(b&7) in [0,96), n0-twin via bit3

typedef float f32x4 __attribute__((ext_vector_type(4)));
typedef __attribute__((ext_vector_type(8))) __bf16 bf16x8;

static __device__ __forceinline__ unsigned short f2bf(float f) {
    union { float f; unsigned u; } v; v.f = f;
    unsigned r = v.u + 0x7FFFu + ((v.u >> 16) & 1u);
    return (unsigned short)(r >> 16);
}
static __device__ __forceinline__ float bflo(unsigned p) {
    union { unsigned u; float f; } v; v.u = p << 16; return v.f;
}
static __device__ __forceinline__ float bfhi(unsigned p) {
    union { unsigned u; float f; } v; v.u = p & 0xFFFF0000u; return v.f;
}
static __device__ __forceinline__ unsigned packbf(float lo, float hi) {
    return (unsigned)f2bf(lo) | ((unsigned)f2bf(hi) << 16);
}

static __device__ __forceinline__ void gload_lds16(const unsigned short* g, unsigned short* l) {
    __builtin_amdgcn_global_load_lds(
        (const __attribute__((address_space(1))) unsigned int*)g,
        (__attribute__((address_space(3))) unsigned int*)l, 16, 0, 0);
}

// ---------- adjacency build: fixed-capacity rows, cursor doubles as deg ----------
__global__ void k_scatter(const int* __restrict__ src, const int* __restrict__ dst,
                          int* __restrict__ cursor, int* __restrict__ eidx2) {
    int e = blockIdx.x * 256 + threadIdx.x;
    if (e >= N_EDGES) return;
    int v = dst[e];
    int slot = atomicAdd(&cursor[v], 1);
    if (slot < CAP) eidx2[v * CAP + slot] = src[e];
}

// ---------- fused: feats->bf16 cast + weight transpose + degree bucketing ----------
__global__ __launch_bounds__(256)
void k_prep(const float* __restrict__ feats, const float* __restrict__ Wl,
            const float* __restrict__ Wr, const int* __restrict__ cursor,
            unsigned short* __restrict__ X, unsigned short* __restrict__ Wt,
            int* __restrict__ bucket_cnt, int* __restrict__ bucket_nodes) {
    int b = blockIdx.x;
    int t = threadIdx.x;
    if (b < CAST_BLOCKS) {
        int n = b * 4 + (t >> 6);
        int col = (t & 63) * 8;
        f32x4 a = *(const f32x4*)(feats + (size_t)n * DIN + col);
        f32x4 c = *(const f32x4*)(feats + (size_t)n * DIN + col + 4);
        uint4 p;
        p.x = packbf(a[0], a[1]); p.y = packbf(a[2], a[3]);
        p.z = packbf(c[0], c[1]); p.w = packbf(c[2], c[3]);
        *(uint4*)(X + (size_t)n * KDIM + DIN + col) = p;
        return;
    }
    if (b < CAST_BLOCKS + WT_BLOCKS) {
        __shared__ float tile[32][33];
        int idx = b - CAST_BLOCKS;
        int d = idx / (32 * 16);
        int rem = idx % (32 * 16);
        int k0 = (rem & 31) * 32;
        int n0 = (rem >> 5) * 32;
        int c = t & 31, r0 = t >> 5;
        const float* srcp = (k0 < DIN) ? (Wl + (size_t)d * DIN * DOUT)
                                       : (Wr + (size_t)d * DIN * DOUT - (size_t)DIN * DOUT);
        for (int rr = 0; rr < 4; ++rr) {
            int r = r0 + rr * 8;
            tile[r][c] = srcp[(size_t)(k0 + r) * DOUT + n0 + c];
        }
        __syncthreads();
        for (int rr = 0; rr < 4; ++rr) {
            int r = r0 + rr * 8;
            Wt[((size_t)d * DOUT + n0 + r) * KDIM + k0 + c] = f2bf(tile[c][r]);
        }
        return;
    }
    // bucketing: two-phase LDS counting sort
    __shared__ int lhist[NBUCKET];
    __shared__ int lbase[NBUCKET];
    if (t < NBUCKET) lhist[t] = 0;
    __syncthreads();
    int v = (b - CAST_BLOCKS - WT_BLOCKS) * 256 + t;
    int d = -1, slot = 0;
    if (v < N_NODES) {
        d = min(cursor[v], NBUCKET - 1);
        slot = atomicAdd(&lhist[d], 1);
    }
    __syncthreads();
    if (t < NBUCKET && lhist[t] > 0) lbase[t] = atomicAdd(&bucket_cnt[t], lhist[t]);
    __syncthreads();
    if (v < N_NODES) bucket_nodes[d * N_NODES + lbase[d] + slot] = v;
}

// ---------- h = sum of neighbor bf16 rows (one wave per node) ----------
__global__ __launch_bounds__(256)
void k_build_x(const int* __restrict__ eidx2, const int* __restrict__ cursor,
               unsigned short* __restrict__ X) {
    int n = blockIdx.x * 4 + (threadIdx.x >> 6);
    int col = (threadIdx.x & 63) * 8;
    const int* adj = eidx2 + (size_t)n * CAP;
    int e = min(cursor[n], CAP);
    float acc[8] = {0,0,0,0,0,0,0,0};
    int i = 0;
    for (; i + 3 < e; i += 4) {
        int u0 = adj[i], u1 = adj[i+1], u2 = adj[i+2], u3 = adj[i+3];
        uint4 p0 = *(const uint4*)(X + (size_t)u0 * KDIM + DIN + col);
        uint4 p1 = *(const uint4*)(X + (size_t)u1 * KDIM + DIN + col);
        uint4 p2 = *(const uint4*)(X + (size_t)u2 * KDIM + DIN + col);
        uint4 p3 = *(const uint4*)(X + (size_t)u3 * KDIM + DIN + col);
        acc[0] += bflo(p0.x) + bflo(p1.x) + bflo(p2.x) + bflo(p3.x);
        acc[1] += bfhi(p0.x) + bfhi(p1.x) + bfhi(p2.x) + bfhi(p3.x);
        acc[2] += bflo(p0.y) + bflo(p1.y) + bflo(p2.y) + bflo(p3.y);
        acc[3] += bfhi(p0.y) + bfhi(p1.y) + bfhi(p2.y) + bfhi(p3.y);
        acc[4] += bflo(p0.z) + bflo(p1.z) + bflo(p2.z) + bflo(p3.z);
        acc[5] += bfhi(p0.z) + bfhi(p1.z) + bfhi(p2.z) + bfhi(p3.z);
        acc[6] += bflo(p0.w) + bflo(p1.w) + bflo(p2.w) + bflo(p3.w);
        acc[7] += bfhi(p0.w) + bfhi(p1.w) + bfhi(p2.w) + bfhi(p3.w);
    }
    for (; i < e; ++i) {
        int u = adj[i];
        uint4 p = *(const uint4*)(X + (size_t)u * KDIM + DIN + col);
        acc[0] += bflo(p.x); acc[1] += bfhi(p.x); acc[2] += bflo(p.y); acc[3] += bfhi(p.y);
        acc[4] += bflo(p.z); acc[5] += bfhi(p.z); acc[6] += bflo(p.w); acc[7] += bfhi(p.w);
    }
    uint4 o;
    o.x = packbf(acc[0], acc[1]); o.y = packbf(acc[2], acc[3]);
    o.z = packbf(acc[4], acc[5]); o.w = packbf(acc[6], acc[7]);
    *(uint4*)(X + (size_t)n * KDIM + col) = o;
}

// ---------- bucketed MFMA GEMM, 256x256 tile, 8 waves, 32-k phases ----------
// Counted-vmcnt pipeline, prefetch distance 3: four 16KB half-tile slots per
// operand indexed by phase&3; STAGE(p+3) issued at phase p (12 loads in
// flight), vmcnt(8) retires phase p+1's loads at end of phase p. Never
// drains in the main loop. XCD-twin grid mapping: tile=(b>>4)*8+(b&7),
// n0=((b>>3)&1)*256 -> the two n0-halves of a tile share an XCD (b mod 8
// equal) so the twin's A-panel re-read hits that XCD's L2.
__global__ __launch_bounds__(512, 2)
void k_gemm(const unsigned short* __restrict__ X, const unsigned short* __restrict__ Wt,
            const int* __restrict__ bucket_nodes, const int* __restrict__ bucket_cnt,
            const float* __restrict__ bl, unsigned short* __restrict__ out_pre,
            float* __restrict__ bn_sum, float* __restrict__ bn_sumsq) {
    int b = blockIdx.x;
    int tile = (b >> 4) * 8 + (b & 7);
    int n0 = ((b >> 3) & 1) * 256;
    // derive (d, m0) from tile index over 256-row tiles
    int d = -1, m0 = 0, accum = 0, cnt = 0;
    for (int bb = 0; bb < NBUCKET; ++bb) {
        int c = bucket_cnt[bb];
        int nt = (c + 255) >> 8;
        if (d < 0 && tile < accum + nt) { d = bb; m0 = (tile - accum) * 256; cnt = c; }
        accum += nt;
    }
    if (d < 0) return;

    // 4 slots of 256 rows x 32 k (64B rows) per operand. Swizzle: slot s of
    // row r holds global k-seg s ^ ((r>>1)&3) (involution; linear LDS dest +
    // pre-swizzled global source per rule 21).
    __shared__ __align__(16) unsigned short AkLds[4][256 * 32];
    __shared__ __align__(16) unsigned short BkLds[4][256 * 32];
    __shared__ int ridS[256];
    __shared__ float colsum[256], colsq[256];

    int t = threadIdx.x;
    if (t < 256) {
        int gm = m0 + t;
        ridS[t] = (gm < cnt) ? bucket_nodes[d * N_NODES + gm] : -1;
        colsum[t] = 0.f; colsq[t] = 0.f;
    }
    __syncthreads();

    int w = t >> 6, l = t & 63;
    int wr = w >> 2, wc = w & 3;           // 2x4 wave grid; wave owns 128x64
    int lm = l & 15, q = l >> 4;

    // ----- staging addressing: thread t covers rows (t>>2) and 128+(t>>2) -----
    int srow = t >> 2;
    int sslot = t & 3;
    int seg = sslot ^ ((srow >> 1) & 3);   // same for srow+128 (bit7 untouched)
    int ridA0 = max(ridS[srow], 0);
    int ridA1 = max(ridS[srow + 128], 0);
    const unsigned short* gA0 = X + (size_t)ridA0 * KDIM + seg * 8;
    const unsigned short* gA1 = X + (size_t)ridA1 * KDIM + seg * 8;
    const unsigned short* gB0 = Wt + ((size_t)d * DOUT + n0 + srow) * KDIM + seg * 8;
    const unsigned short* gB1 = Wt + ((size_t)d * DOUT + n0 + srow + 128) * KDIM + seg * 8;

    // ----- fragment-read addressing -----
    int swz = (lm >> 1) & 3;
    int slotrd = ((q ^ swz) & 3) * 8;              // element offset of the 8-elem seg
    int aoff = (wr * 128 + lm) * 32 + slotrd;      // + mf*512
    int boff = (wc * 64 + lm) * 32 + slotrd;       // + nf*512

    f32x4 acc[8][4];
#pragma unroll
    for (int i = 0; i < 8; ++i)
#pragma unroll
        for (int j = 0; j < 4; ++j) acc[i][j] = (f32x4){0, 0, 0, 0};

    // STAGE(q): stage global k range [q*32, q*32+32) into slot q&3
    auto STAGE = [&](int qq) {
        int go = qq * 32;
        int sl = qq & 3;
        gload_lds16(gA0 + go, &AkLds[sl][w * 512]);
        gload_lds16(gA1 + go, &AkLds[sl][4096 + w * 512]);
        gload_lds16(gB0 + go, &BkLds[sl][w * 512]);
        gload_lds16(gB1 + go, &BkLds[sl][4096 + w * 512]);
    };
    auto COMPUTE = [&](int ph) {
        int sl = ph & 3;
        bf16x8 af[8], bfr[4];
        const unsigned short* Ab = &AkLds[sl][0];
        const unsigned short* Bb = &BkLds[sl][0];
#pragma unroll
        for (int mf = 0; mf < 8; ++mf)
            af[mf] = *(const bf16x8*)&Ab[aoff + mf * 512];
#pragma unroll
        for (int nf = 0; nf < 4; ++nf)
            bfr[nf] = *(const bf16x8*)&Bb[boff + nf * 512];
        __builtin_amdgcn_s_setprio(1);
#pragma unroll
        for (int mf = 0; mf < 8; ++mf)
#pragma unroll
            for (int nf = 0; nf < 4; ++nf)
                acc[mf][nf] = __builtin_amdgcn_mfma_f32_16x16x32_bf16(af[mf], bfr[nf], acc[mf][nf], 0, 0, 0);
        __builtin_amdgcn_s_setprio(0);
    };

    // prologue: stage phases 0..2 (12 loads), wait phase 0 landed (8 left)
    STAGE(0); STAGE(1); STAGE(2);
    asm volatile("s_waitcnt vmcnt(8)" ::: "memory");
    __builtin_amdgcn_s_barrier();
    asm volatile("" ::: "memory");

#pragma unroll 1
    for (int p = 0; p < 32; ++p) {
        if (p < 29) STAGE(p + 3);   // into slot (p-1)&3, freed at end of phase p-1
        COMPUTE(p);
        // retire phase p+1's loads (issued at phase p-2): 12 outstanding -> 8
        if (p < 29)       asm volatile("s_waitcnt vmcnt(8)" ::: "memory");
        else if (p == 29) asm volatile("s_waitcnt vmcnt(4)" ::: "memory");
        else              asm volatile("s_waitcnt vmcnt(0)" ::: "memory");
        __builtin_amdgcn_s_barrier();
        asm volatile("" ::: "memory");
    }

    // ---- epilogue: bias + bf16 store + BN partial sums ----
    const float* blr = bl + d * DOUT + n0;
    float vsum[4] = {0, 0, 0, 0}, vsq[4] = {0, 0, 0, 0};
#pragma unroll
    for (int mf = 0; mf < 8; ++mf) {
#pragma unroll
        for (int rr = 0; rr < 4; ++rr) {
            int row = wr * 128 + mf * 16 + q * 4 + rr;
            int grow = ridS[row];
            if (grow < 0) continue;
            unsigned short* orow = out_pre + (size_t)grow * DOUT + n0;
#pragma unroll
            for (int nf = 0; nf < 4; ++nf) {
                int col = wc * 64 + nf * 16 + lm;
                float v = acc[mf][nf][rr] + blr[col];
                orow[col] = f2bf(v);
                vsum[nf] += v; vsq[nf] += v * v;
            }
        }
    }
#pragma unroll
    for (int nf = 0; nf < 4; ++nf) {
        vsum[nf] += __shfl_xor(vsum[nf], 16, 64);
        vsum[nf] += __shfl_xor(vsum[nf], 32, 64);
        vsq[nf]  += __shfl_xor(vsq[nf], 16, 64);
        vsq[nf]  += __shfl_xor(vsq[nf], 32, 64);
    }
    if (q == 0) {
#pragma unroll
        for (int nf = 0; nf < 4; ++nf) {
            atomicAdd(&colsum[wc * 64 + nf * 16 + lm], vsum[nf]);
            atomicAdd(&colsq[wc * 64 + nf * 16 + lm], vsq[nf]);
        }
    }
    __syncthreads();
    if (t < 256) {
        atomicAdd(&bn_sum[n0 + t], colsum[t]);
        atomicAdd(&bn_sumsq[n0 + t], colsq[t]);
    }
}

// ---------- fused BN-final + segment_max + BN-apply (one wave per node) ----------
__global__ __launch_bounds__(256)
void k_max(const unsigned short* __restrict__ out_pre, const int* __restrict__ eidx2,
           const int* __restrict__ cursor, const float* __restrict__ bn_sum,
           const float* __restrict__ bn_sumsq, const float* __restrict__ gamma,
           const float* __restrict__ beta, float* __restrict__ out) {
    int n = blockIdx.x * 4 + (threadIdx.x >> 6);
    int col = (threadIdx.x & 63) * 8;
    const int* adj = eidx2 + (size_t)n * CAP;
    int e = min(cursor[n], CAP);
    float mx[8];
    {
        uint4 p = *(const uint4*)(out_pre + (size_t)n * DOUT + col);
        mx[0] = bflo(p.x); mx[1] = bfhi(p.x); mx[2] = bflo(p.y); mx[3] = bfhi(p.y);
        mx[4] = bflo(p.z); mx[5] = bfhi(p.z); mx[6] = bflo(p.w); mx[7] = bfhi(p.w);
    }
    int i = 0;
    for (; i + 3 < e; i += 4) {
        int u0 = adj[i], u1 = adj[i+1], u2 = adj[i+2], u3 = adj[i+3];
        uint4 p0 = *(const uint4*)(out_pre + (size_t)u0 * DOUT + col);
        uint4 p1 = *(const uint4*)(out_pre + (size_t)u1 * DOUT + col);
        uint4 p2 = *(const uint4*)(out_pre + (size_t)u2 * DOUT + col);
        uint4 p3 = *(const uint4*)(out_pre + (size_t)u3 * DOUT + col);
        mx[0] = fmaxf(mx[0], fmaxf(fmaxf(bflo(p0.x), bflo(p1.x)), fmaxf(bflo(p2.x), bflo(p3.x))));
        mx[1] = fmaxf(mx[1], fmaxf(fmaxf(bfhi(p0.x), bfhi(p1.x)), fmaxf(bfhi(p2.x), bfhi(p3.x))));
        mx[2] = fmaxf(mx[2], fmaxf(fmaxf(bflo(p0.y), bflo(p1.y)), fmaxf(bflo(p2.y), bflo(p3.y))));
        mx[3] = fmaxf(mx[3], fmaxf(fmaxf(bfhi(p0.y), bfhi(p1.y)), fmaxf(bfhi(p2.y), bfhi(p3.y))));
        mx[4] = fmaxf(mx[4], fmaxf(fmaxf(bflo(p0.z), bflo(p1.z)), fmaxf(bflo(p2.z), bflo(p3.z))));
        mx[5] = fmaxf(mx[5], fmaxf(fmaxf(bfhi(p0.z), bfhi(p1.z)), fmaxf(bfhi(p2.z), bfhi(p3.z))));
        mx[6] = fmaxf(mx[6], fmaxf(fmaxf(bflo(p0.w), bflo(p1.w)), fmaxf(bflo(p2.w), bflo(p3.w))));
        mx[7] = fmaxf(mx[7], fmaxf(fmaxf(bfhi(p0.w), bfhi(p1.w)), fmaxf(bfhi(p2.w), bfhi(p3.w))));
    }
    for (; i < e; ++i) {
        int u = adj[i];
        uint4 p = *(const uint4*)(out_pre + (size_t)u * DOUT + col);
        mx[0] = fmaxf(mx[0], bflo(p.x)); mx[1] = fmaxf(mx[1], bfhi(p.x));
        mx[2] = fmaxf(mx[2], bflo(p.y)); mx[3] = fmaxf(mx[3], bfhi(p.y));
        mx[4] = fmaxf(mx[4], bflo(p.z)); mx[5] = fmaxf(mx[5], bfhi(p.z));
        mx[6] = fmaxf(mx[6], bflo(p.w)); mx[7] = fmaxf(mx[7], bfhi(p.w));
    }
    const float inv_n = 1.0f / (float)N_NODES;
    f32x4 r0, r1;
#pragma unroll
    for (int jj = 0; jj < 8; ++jj) {
        int c = col + jj;
        float mean = bn_sum[c] * inv_n;
        float var = bn_sumsq[c] * inv_n - mean * mean;
        float sc = gamma[c] * rsqrtf(var + BN_EPS);
        float sh = beta[c] - mean * sc;
        float v = mx[jj] * sc + sh;
        if (jj < 4) r0[jj] = v; else r1[jj - 4] = v;
    }
    *(f32x4*)(out + (size_t)n * DOUT + col) = r0;
    *(f32x4*)(out + (size_t)n * DOUT + col + 4) = r1;
}

extern "C" void kernel_launch(void* const* d_in, const int* in_sizes, int n_in,
                              void* d_out, int out_size, void* d_ws, size_t ws_size,
                              hipStream_t stream) {
    const float* feats = (const float*)d_in[0];
    const int*   src   = (const int*)d_in[1];
    const int*   dst   = (const int*)d_in[2];
    const float* Wl    = (const float*)d_in[3];
    const float* Wr    = (const float*)d_in[4];
    const float* bl    = (const float*)d_in[5];
    const float* gamma = (const float*)d_in[6];
    const float* beta  = (const float*)d_in[7];
    float* out = (float*)d_out;

    char* ws = (char*)d_ws;
    size_t off = 0;
    auto alloc = [&](size_t bytes) -> void* {
        off = (off + 255) & ~(size_t)255;
        void* p = ws + off;
        off += bytes;
        return p;
    };

    // zero-initialized region (contiguous & first)
    int*   cursor     = (int*)alloc(N_NODES * 4);
    int*   bucket_cnt = (int*)alloc(16 * 4);
    float* bn_sum     = (float*)alloc(DOUT * 4);
    float* bn_sumsq   = (float*)alloc(DOUT * 4);
    size_t zbytes = off;

    int* bucket_nodes = (int*)alloc((size_t)NBUCKET * N_NODES * 4);
    int* eidx2        = (int*)alloc((size_t)N_NODES * CAP * 4);
    unsigned short* X  = (unsigned short*)alloc((size_t)N_NODES * KDIM * 2);
    unsigned short* Wt = (unsigned short*)alloc((size_t)NBUCKET * DOUT * KDIM * 2);
    unsigned short* out_pre = (unsigned short*)alloc((size_t)N_NODES * DOUT * 2);

    hipMemsetAsync(d_ws, 0, zbytes, stream);

    k_scatter<<<(N_EDGES + 255) / 256, 256, 0, stream>>>(src, dst, cursor, eidx2);
    k_prep<<<CAST_BLOCKS + WT_BLOCKS + BUCKET_BLOCKS, 256, 0, stream>>>(
        feats, Wl, Wr, cursor, X, Wt, bucket_cnt, bucket_nodes);
    k_build_x<<<N_NODES / 4, 256, 0, stream>>>(eidx2, cursor, X);
    k_gemm<<<dim3(GEMM_BLOCKS), 512, 0, stream>>>(
        X, Wt, bucket_nodes, bucket_cnt, bl, out_pre, bn_sum, bn_sumsq);
    k_max<<<N_NODES / 4, 256, 0, stream>>>(out_pre, eidx2, cursor, bn_sum, bn_sumsq, gamma, beta, out);
}

// Round 4
// 218.846 us; speedup vs baseline: 1.0809x; 1.0809x over previous
//
#include <hip/hip_runtime.h>
#include <hip/hip_bf16.h>
#include <stdint.h>

#define N_NODES 20000
#define N_EDGES 160000
#define DIN 512
#define DOUT 512
#define NBUCKET 11
#define KDIM 1024   // [h | feats]
#define MAXTILES 168   // sum_d ceil(cnt_d/128) <= floor(20000/128)+11
#define BN_EPS 1e-5f
#define CAP 64         // fixed adjacency capacity; deg is Poisson(8), P(>=64) ~ 1e-40
#define CAST_BLOCKS (N_NODES / 4)                  // 5000 (4 rows / 256-thr block)
#define WT_BLOCKS ((KDIM / 32) * (DOUT / 32) * NBUCKET)  // 5632
#define BUCKET_BLOCKS ((N_NODES + 255) / 256)      // 79

typedef float f32x4 __attribute__((ext_vector_type(4)));
typedef __attribute__((ext_vector_type(8))) __bf16 bf16x8;

static __device__ __forceinline__ unsigned short f2bf(float f) {
    union { float f; unsigned u; } v; v.f = f;
    unsigned r = v.u + 0x7FFFu + ((v.u >> 16) & 1u);
    return (unsigned short)(r >> 16);
}
static __device__ __forceinline__ float bflo(unsigned p) {
    union { unsigned u; float f; } v; v.u = p << 16; return v.f;
}
static __device__ __forceinline__ float bfhi(unsigned p) {
    union { unsigned u; float f; } v; v.u = p & 0xFFFF0000u; return v.f;
}
static __device__ __forceinline__ unsigned packbf(float lo, float hi) {
    return (unsigned)f2bf(lo) | ((unsigned)f2bf(hi) << 16);
}

static __device__ __forceinline__ void gload_lds16(const unsigned short* g, unsigned short* l) {
    __builtin_amdgcn_global_load_lds(
        (const __attribute__((address_space(1))) unsigned int*)g,
        (__attribute__((address_space(3))) unsigned int*)l, 16, 0, 0);
}

// ---------- adjacency build: fixed-capacity rows, cursor doubles as deg ----------
__global__ void k_scatter(const int* __restrict__ src, const int* __restrict__ dst,
                          int* __restrict__ cursor, int* __restrict__ eidx2) {
    int e = blockIdx.x * 256 + threadIdx.x;
    if (e >= N_EDGES) return;
    int v = dst[e];
    int slot = atomicAdd(&cursor[v], 1);
    if (slot < CAP) eidx2[v * CAP + slot] = src[e];
}

// ---------- fused: feats->bf16 cast + weight transpose + degree bucketing ----------
__global__ __launch_bounds__(256)
void k_prep(const float* __restrict__ feats, const float* __restrict__ Wl,
            const float* __restrict__ Wr, const int* __restrict__ cursor,
            unsigned short* __restrict__ X, unsigned short* __restrict__ Wt,
            int* __restrict__ bucket_cnt, int* __restrict__ bucket_nodes) {
    int b = blockIdx.x;
    int t = threadIdx.x;
    if (b < CAST_BLOCKS) {
        int n = b * 4 + (t >> 6);
        int col = (t & 63) * 8;
        f32x4 a = *(const f32x4*)(feats + (size_t)n * DIN + col);
        f32x4 c = *(const f32x4*)(feats + (size_t)n * DIN + col + 4);
        uint4 p;
        p.x = packbf(a[0], a[1]); p.y = packbf(a[2], a[3]);
        p.z = packbf(c[0], c[1]); p.w = packbf(c[2], c[3]);
        *(uint4*)(X + (size_t)n * KDIM + DIN + col) = p;
        return;
    }
    if (b < CAST_BLOCKS + WT_BLOCKS) {
        __shared__ float tile[32][33];
        int idx = b - CAST_BLOCKS;
        int d = idx / (32 * 16);
        int rem = idx % (32 * 16);
        int k0 = (rem & 31) * 32;
        int n0 = (rem >> 5) * 32;
        int c = t & 31, r0 = t >> 5;
        const float* srcp = (k0 < DIN) ? (Wl + (size_t)d * DIN * DOUT)
                                       : (Wr + (size_t)d * DIN * DOUT - (size_t)DIN * DOUT);
        for (int rr = 0; rr < 4; ++rr) {
            int r = r0 + rr * 8;
            tile[r][c] = srcp[(size_t)(k0 + r) * DOUT + n0 + c];
        }
        __syncthreads();
        for (int rr = 0; rr < 4; ++rr) {
            int r = r0 + rr * 8;
            Wt[((size_t)d * DOUT + n0 + r) * KDIM + k0 + c] = f2bf(tile[c][r]);
        }
        return;
    }
    // bucketing: two-phase LDS counting sort
    __shared__ int lhist[NBUCKET];
    __shared__ int lbase[NBUCKET];
    if (t < NBUCKET) lhist[t] = 0;
    __syncthreads();
    int v = (b - CAST_BLOCKS - WT_BLOCKS) * 256 + t;
    int d = -1, slot = 0;
    if (v < N_NODES) {
        d = min(cursor[v], NBUCKET - 1);
        slot = atomicAdd(&lhist[d], 1);
    }
    __syncthreads();
    if (t < NBUCKET && lhist[t] > 0) lbase[t] = atomicAdd(&bucket_cnt[t], lhist[t]);
    __syncthreads();
    if (v < N_NODES) bucket_nodes[d * N_NODES + lbase[d] + slot] = v;
}

// ---------- h = sum of neighbor bf16 rows (one wave per node) ----------
// Adjacency indices preloaded once (lane l holds adj[l], one coalesced 256B
// load) and distributed via __shfl -> index fetch off the critical path.
// 8 independent row-gathers in flight (deg is Poisson(8): one latency round
// covers most nodes), then 4/1 tails.
__global__ __launch_bounds__(256)
void k_build_x(const int* __restrict__ eidx2, const int* __restrict__ cursor,
               unsigned short* __restrict__ X) {
    int n = blockIdx.x * 4 + (threadIdx.x >> 6);
    int lane = threadIdx.x & 63;
    int col = lane * 8;
    int e = min(cursor[n], CAP);
    int av = eidx2[(size_t)n * CAP + lane];   // lane l holds adj[l] (garbage for l>=e, unused)
    float acc[8] = {0,0,0,0,0,0,0,0};
    int i = 0;
    for (; i + 7 < e; i += 8) {
        uint4 p[8];
#pragma unroll
        for (int j = 0; j < 8; ++j) {
            int u = __shfl(av, i + j, 64);
            p[j] = *(const uint4*)(X + (size_t)u * KDIM + DIN + col);
        }
#pragma unroll
        for (int j = 0; j < 8; ++j) {
            acc[0] += bflo(p[j].x); acc[1] += bfhi(p[j].x);
            acc[2] += bflo(p[j].y); acc[3] += bfhi(p[j].y);
            acc[4] += bflo(p[j].z); acc[5] += bfhi(p[j].z);
            acc[6] += bflo(p[j].w); acc[7] += bfhi(p[j].w);
        }
    }
    if (i + 3 < e) {
        uint4 p[4];
#pragma unroll
        for (int j = 0; j < 4; ++j) {
            int u = __shfl(av, i + j, 64);
            p[j] = *(const uint4*)(X + (size_t)u * KDIM + DIN + col);
        }
#pragma unroll
        for (int j = 0; j < 4; ++j) {
            acc[0] += bflo(p[j].x); acc[1] += bfhi(p[j].x);
            acc[2] += bflo(p[j].y); acc[3] += bfhi(p[j].y);
            acc[4] += bflo(p[j].z); acc[5] += bfhi(p[j].z);
            acc[6] += bflo(p[j].w); acc[7] += bfhi(p[j].w);
        }
        i += 4;
    }
    for (; i < e; ++i) {
        int u = __shfl(av, i, 64);
        uint4 p = *(const uint4*)(X + (size_t)u * KDIM + DIN + col);
        acc[0] += bflo(p.x); acc[1] += bfhi(p.x); acc[2] += bflo(p.y); acc[3] += bfhi(p.y);
        acc[4] += bflo(p.z); acc[5] += bfhi(p.z); acc[6] += bflo(p.w); acc[7] += bfhi(p.w);
    }
    uint4 o;
    o.x = packbf(acc[0], acc[1]); o.y = packbf(acc[2], acc[3]);
    o.z = packbf(acc[4], acc[5]); o.w = packbf(acc[6], acc[7]);
    *(uint4*)(X + (size_t)n * KDIM + col) = o;
}

// ---------- bucketed MFMA GEMM, 128x128 tile, BK=64, swizzled LDS ----------
// (round-0 structure, verbatim: best measured 40.5us; TLP across ~2.6
// blocks/CU beats every explicit-pipeline variant tried in R1-R3)
__global__ __launch_bounds__(256)
void k_gemm(const unsigned short* __restrict__ X, const unsigned short* __restrict__ Wt,
            const int* __restrict__ bucket_nodes, const int* __restrict__ bucket_cnt,
            const float* __restrict__ bl, unsigned short* __restrict__ out_pre,
            float* __restrict__ bn_sum, float* __restrict__ bn_sumsq) {
    // derive (d, m0) from linear tile index over 128-row tiles
    int idx = blockIdx.x;
    int d = -1, m0 = 0, accum = 0, cnt = 0;
    for (int b = 0; b < NBUCKET; ++b) {
        int c = bucket_cnt[b];
        int nt = (c + 127) >> 7;
        if (d < 0 && idx < accum + nt) { d = b; m0 = (idx - accum) * 128; cnt = c; }
        accum += nt;
    }
    if (d < 0) return;
    int n0 = blockIdx.y * 128;

    // rows of 128B (=32 banks); slot p of row holds global k-segment p^(row&7)
    __shared__ __align__(16) unsigned short As[128 * 64];
    __shared__ __align__(16) unsigned short Bs[128 * 64];
    __shared__ int ridS[128];
    __shared__ float colsum[128], colsq[128];

    int t = threadIdx.x;
    if (t < 128) {
        int gm = m0 + t;
        ridS[t] = (gm < cnt) ? bucket_nodes[d * N_NODES + gm] : -1;
        colsum[t] = 0.f; colsq[t] = 0.f;
    }
    __syncthreads();

    int lane = t & 63, w = t >> 6;
    int r = lane >> 3;          // row within 8-row staging group
    int s = lane & 7;           // LDS slot
    int sg = s ^ r;             // swizzled global segment

    const unsigned short* gA[4];
    const unsigned short* gB[4];
    unsigned short* lA[4];
    unsigned short* lB[4];
#pragma unroll
    for (int j = 0; j < 4; ++j) {
        int row = w * 32 + j * 8 + r;
        int rid = max(ridS[row], 0);
        gA[j] = X + (size_t)rid * KDIM + sg * 8;
        gB[j] = Wt + ((size_t)d * DOUT + n0 + row) * KDIM + sg * 8;
        lA[j] = &As[(w * 32 + j * 8) * 64];
        lB[j] = &Bs[(w * 32 + j * 8) * 64];
    }

    int wm = (w & 1) * 64, wn = (w >> 1) * 64;
    int lm = lane & 15, q = lane >> 4;
    int sw = lm & 7;

    f32x4 acc[4][4];
#pragma unroll
    for (int i = 0; i < 4; ++i)
#pragma unroll
        for (int j = 0; j < 4; ++j) acc[i][j] = (f32x4){0, 0, 0, 0};

    for (int kt = 0; kt < KDIM / 64; ++kt) {
#pragma unroll
        for (int j = 0; j < 4; ++j) {
            gload_lds16(gA[j] + kt * 64, lA[j]);
            gload_lds16(gB[j] + kt * 64, lB[j]);
        }
        __syncthreads();

#pragma unroll
        for (int kk = 0; kk < 2; ++kk) {
            int slot = (kk * 4 + q) ^ sw;
            bf16x8 af[4], bfr[4];
#pragma unroll
            for (int mt = 0; mt < 4; ++mt)
                af[mt] = *(bf16x8*)&As[(wm + mt * 16 + lm) * 64 + slot * 8];
#pragma unroll
            for (int nt = 0; nt < 4; ++nt)
                bfr[nt] = *(bf16x8*)&Bs[(wn + nt * 16 + lm) * 64 + slot * 8];
#pragma unroll
            for (int mt = 0; mt < 4; ++mt)
#pragma unroll
                for (int nt = 0; nt < 4; ++nt)
                    acc[mt][nt] = __builtin_amdgcn_mfma_f32_16x16x32_bf16(af[mt], bfr[nt], acc[mt][nt], 0, 0, 0);
        }
        __syncthreads();
    }

    const float* blr = bl + d * DOUT + n0;
    float vsum[4] = {0, 0, 0, 0}, vsq[4] = {0, 0, 0, 0};
#pragma unroll
    for (int mt = 0; mt < 4; ++mt) {
#pragma unroll
        for (int rr = 0; rr < 4; ++rr) {
            int row = wm + mt * 16 + q * 4 + rr;
            int grow = ridS[row];
            if (grow < 0) continue;
            unsigned short* orow = out_pre + (size_t)grow * DOUT + n0;
#pragma unroll
            for (int nt = 0; nt < 4; ++nt) {
                int col = wn + nt * 16 + lm;
                float v = acc[mt][nt][rr] + blr[col];
                orow[col] = f2bf(v);
                vsum[nt] += v; vsq[nt] += v * v;
            }
        }
    }
#pragma unroll
    for (int nt = 0; nt < 4; ++nt) {
        vsum[nt] += __shfl_xor(vsum[nt], 16, 64);
        vsum[nt] += __shfl_xor(vsum[nt], 32, 64);
        vsq[nt]  += __shfl_xor(vsq[nt], 16, 64);
        vsq[nt]  += __shfl_xor(vsq[nt], 32, 64);
    }
    if (q == 0) {
#pragma unroll
        for (int nt = 0; nt < 4; ++nt) {
            atomicAdd(&colsum[wn + nt * 16 + lm], vsum[nt]);
            atomicAdd(&colsq[wn + nt * 16 + lm], vsq[nt]);
        }
    }
    __syncthreads();
    if (t < 128) {
        atomicAdd(&bn_sum[n0 + t], colsum[t]);
        atomicAdd(&bn_sumsq[n0 + t], colsq[t]);
    }
}

// ---------- fused BN-final + segment_max + BN-apply (one wave per node) ----------
// Same gather restructure as k_build_x: lane-broadcast adjacency + 8-deep MLP.
// BN params loaded as f32x4 pairs.
__global__ __launch_bounds__(256)
void k_max(const unsigned short* __restrict__ out_pre, const int* __restrict__ eidx2,
           const int* __restrict__ cursor, const float* __restrict__ bn_sum,
           const float* __restrict__ bn_sumsq, const float* __restrict__ gamma,
           const float* __restrict__ beta, float* __restrict__ out) {
    int n = blockIdx.x * 4 + (threadIdx.x >> 6);
    int lane = threadIdx.x & 63;
    int col = lane * 8;
    int e = min(cursor[n], CAP);
    int av = eidx2[(size_t)n * CAP + lane];
    float mx[8];
    {
        uint4 p = *(const uint4*)(out_pre + (size_t)n * DOUT + col);
        mx[0] = bflo(p.x); mx[1] = bfhi(p.x); mx[2] = bflo(p.y); mx[3] = bfhi(p.y);
        mx[4] = bflo(p.z); mx[5] = bfhi(p.z); mx[6] = bflo(p.w); mx[7] = bfhi(p.w);
    }
    int i = 0;
    for (; i + 7 < e; i += 8) {
        uint4 p[8];
#pragma unroll
        for (int j = 0; j < 8; ++j) {
            int u = __shfl(av, i + j, 64);
            p[j] = *(const uint4*)(out_pre + (size_t)u * DOUT + col);
        }
#pragma unroll
        for (int j = 0; j < 8; ++j) {
            mx[0] = fmaxf(mx[0], bflo(p[j].x)); mx[1] = fmaxf(mx[1], bfhi(p[j].x));
            mx[2] = fmaxf(mx[2], bflo(p[j].y)); mx[3] = fmaxf(mx[3], bfhi(p[j].y));
            mx[4] = fmaxf(mx[4], bflo(p[j].z)); mx[5] = fmaxf(mx[5], bfhi(p[j].z));
            mx[6] = fmaxf(mx[6], bflo(p[j].w)); mx[7] = fmaxf(mx[7], bfhi(p[j].w));
        }
    }
    if (i + 3 < e) {
        uint4 p[4];
#pragma unroll
        for (int j = 0; j < 4; ++j) {
            int u = __shfl(av, i + j, 64);
            p[j] = *(const uint4*)(out_pre + (size_t)u * DOUT + col);
        }
#pragma unroll
        for (int j = 0; j < 4; ++j) {
            mx[0] = fmaxf(mx[0], bflo(p[j].x)); mx[1] = fmaxf(mx[1], bfhi(p[j].x));
            mx[2] = fmaxf(mx[2], bflo(p[j].y)); mx[3] = fmaxf(mx[3], bfhi(p[j].y));
            mx[4] = fmaxf(mx[4], bflo(p[j].z)); mx[5] = fmaxf(mx[5], bfhi(p[j].z));
            mx[6] = fmaxf(mx[6], bflo(p[j].w)); mx[7] = fmaxf(mx[7], bfhi(p[j].w));
        }
        i += 4;
    }
    for (; i < e; ++i) {
        int u = __shfl(av, i, 64);
        uint4 p = *(const uint4*)(out_pre + (size_t)u * DOUT + col);
        mx[0] = fmaxf(mx[0], bflo(p.x)); mx[1] = fmaxf(mx[1], bfhi(p.x));
        mx[2] = fmaxf(mx[2], bflo(p.y)); mx[3] = fmaxf(mx[3], bfhi(p.y));
        mx[4] = fmaxf(mx[4], bflo(p.z)); mx[5] = fmaxf(mx[5], bfhi(p.z));
        mx[6] = fmaxf(mx[6], bflo(p.w)); mx[7] = fmaxf(mx[7], bfhi(p.w));
    }
    const float inv_n = 1.0f / (float)N_NODES;
    f32x4 sm0 = *(const f32x4*)(bn_sum + col);
    f32x4 sm1 = *(const f32x4*)(bn_sum + col + 4);
    f32x4 sq0 = *(const f32x4*)(bn_sumsq + col);
    f32x4 sq1 = *(const f32x4*)(bn_sumsq + col + 4);
    f32x4 g0 = *(const f32x4*)(gamma + col);
    f32x4 g1 = *(const f32x4*)(gamma + col + 4);
    f32x4 b0 = *(const f32x4*)(beta + col);
    f32x4 b1 = *(const f32x4*)(beta + col + 4);
    f32x4 r0, r1;
#pragma unroll
    for (int jj = 0; jj < 4; ++jj) {
        float mean = sm0[jj] * inv_n;
        float var = sq0[jj] * inv_n - mean * mean;
        float sc = g0[jj] * rsqrtf(var + BN_EPS);
        r0[jj] = mx[jj] * sc + (b0[jj] - mean * sc);
    }
#pragma unroll
    for (int jj = 0; jj < 4; ++jj) {
        float mean = sm1[jj] * inv_n;
        float var = sq1[jj] * inv_n - mean * mean;
        float sc = g1[jj] * rsqrtf(var + BN_EPS);
        r1[jj] = mx[jj + 4] * sc + (b1[jj] - mean * sc);
    }
    *(f32x4*)(out + (size_t)n * DOUT + col) = r0;
    *(f32x4*)(out + (size_t)n * DOUT + col + 4) = r1;
}

extern "C" void kernel_launch(void* const* d_in, const int* in_sizes, int n_in,
                              void* d_out, int out_size, void* d_ws, size_t ws_size,
                              hipStream_t stream) {
    const float* feats = (const float*)d_in[0];
    const int*   src   = (const int*)d_in[1];
    const int*   dst   = (const int*)d_in[2];
    const float* Wl    = (const float*)d_in[3];
    const float* Wr    = (const float*)d_in[4];
    const float* bl    = (const float*)d_in[5];
    const float* gamma = (const float*)d_in[6];
    const float* beta  = (const float*)d_in[7];
    float* out = (float*)d_out;

    char* ws = (char*)d_ws;
    size_t off = 0;
    auto alloc = [&](size_t bytes) -> void* {
        off = (off + 255) & ~(size_t)255;
        void* p = ws + off;
        off += bytes;
        return p;
    };

    // zero-initialized region (contiguous & first)
    int*   cursor     = (int*)alloc(N_NODES * 4);
    int*   bucket_cnt = (int*)alloc(16 * 4);
    float* bn_sum     = (float*)alloc(DOUT * 4);
    float* bn_sumsq   = (float*)alloc(DOUT * 4);
    size_t zbytes = off;

    int* bucket_nodes = (int*)alloc((size_t)NBUCKET * N_NODES * 4);
    int* eidx2        = (int*)alloc((size_t)N_NODES * CAP * 4);
    unsigned short* X  = (unsigned short*)alloc((size_t)N_NODES * KDIM * 2);
    unsigned short* Wt = (unsigned short*)alloc((size_t)NBUCKET * DOUT * KDIM * 2);
    unsigned short* out_pre = (unsigned short*)alloc((size_t)N_NODES * DOUT * 2);

    hipMemsetAsync(d_ws, 0, zbytes, stream);

    k_scatter<<<(N_EDGES + 255) / 256, 256, 0, stream>>>(src, dst, cursor, eidx2);
    k_prep<<<CAST_BLOCKS + WT_BLOCKS + BUCKET_BLOCKS, 256, 0, stream>>>(
        feats, Wl, Wr, cursor, X, Wt, bucket_cnt, bucket_nodes);
    k_build_x<<<N_NODES / 4, 256, 0, stream>>>(eidx2, cursor, X);
    k_gemm<<<dim3(MAXTILES, 4), 256, 0, stream>>>(
        X, Wt, bucket_nodes, bucket_cnt, bl, out_pre, bn_sum, bn_sumsq);
    k_max<<<N_NODES / 4, 256, 0, stream>>>(out_pre, eidx2, cursor, bn_sum, bn_sumsq, gamma, beta, out);
}

// Round 5
// 218.166 us; speedup vs baseline: 1.0842x; 1.0031x over previous
//
#include <hip/hip_runtime.h>
#include <hip/hip_bf16.h>
#include <stdint.h>

#define N_NODES 20000
#define N_EDGES 160000
#define DIN 512
#define DOUT 512
#define NBUCKET 11
#define KDIM 1024   // [h | feats]
#define MAXTILES 168   // sum_d ceil(cnt_d/128) <= floor(20000/128)+11
#define BN_EPS 1e-5f
#define CAP 64         // fixed adjacency capacity; deg is Poisson(8), P(>=64) ~ 1e-40
#define CAST_BLOCKS (N_NODES / 4)                  // 5000 (4 rows / 256-thr block)
#define WT_BLOCKS ((KDIM / 32) * (DOUT / 32) * NBUCKET)  // 5632
#define BUCKET_BLOCKS ((N_NODES + 255) / 256)      // 79
#define GEMM_BLOCKS (8 * MAXTILES)   // 1344: b = T%8 + 8*n0q + 64*(T/8), XCD-twin grouped

typedef float f32x4 __attribute__((ext_vector_type(4)));
typedef __attribute__((ext_vector_type(8))) __bf16 bf16x8;

static __device__ __forceinline__ unsigned short f2bf(float f) {
    union { float f; unsigned u; } v; v.f = f;
    unsigned r = v.u + 0x7FFFu + ((v.u >> 16) & 1u);
    return (unsigned short)(r >> 16);
}
static __device__ __forceinline__ float bflo(unsigned p) {
    union { unsigned u; float f; } v; v.u = p << 16; return v.f;
}
static __device__ __forceinline__ float bfhi(unsigned p) {
    union { unsigned u; float f; } v; v.u = p & 0xFFFF0000u; return v.f;
}
static __device__ __forceinline__ unsigned packbf(float lo, float hi) {
    return (unsigned)f2bf(lo) | ((unsigned)f2bf(hi) << 16);
}

static __device__ __forceinline__ void gload_lds16(const unsigned short* g, unsigned short* l) {
    __builtin_amdgcn_global_load_lds(
        (const __attribute__((address_space(1))) unsigned int*)g,
        (__attribute__((address_space(3))) unsigned int*)l, 16, 0, 0);
}

// ---------- adjacency build: fixed-capacity rows, cursor doubles as deg ----------
__global__ void k_scatter(const int* __restrict__ src, const int* __restrict__ dst,
                          int* __restrict__ cursor, int* __restrict__ eidx2) {
    int e = blockIdx.x * 256 + threadIdx.x;
    if (e >= N_EDGES) return;
    int v = dst[e];
    int slot = atomicAdd(&cursor[v], 1);
    if (slot < CAP) eidx2[v * CAP + slot] = src[e];
}

// ---------- fused: feats->bf16 cast + weight transpose + degree bucketing ----------
__global__ __launch_bounds__(256)
void k_prep(const float* __restrict__ feats, const float* __restrict__ Wl,
            const float* __restrict__ Wr, const int* __restrict__ cursor,
            unsigned short* __restrict__ X, unsigned short* __restrict__ Wt,
            int* __restrict__ bucket_cnt, int* __restrict__ bucket_nodes) {
    int b = blockIdx.x;
    int t = threadIdx.x;
    if (b < CAST_BLOCKS) {
        int n = b * 4 + (t >> 6);
        int col = (t & 63) * 8;
        f32x4 a = *(const f32x4*)(feats + (size_t)n * DIN + col);
        f32x4 c = *(const f32x4*)(feats + (size_t)n * DIN + col + 4);
        uint4 p;
        p.x = packbf(a[0], a[1]); p.y = packbf(a[2], a[3]);
        p.z = packbf(c[0], c[1]); p.w = packbf(c[2], c[3]);
        *(uint4*)(X + (size_t)n * KDIM + DIN + col) = p;
        return;
    }
    if (b < CAST_BLOCKS + WT_BLOCKS) {
        __shared__ float tile[32][33];
        int idx = b - CAST_BLOCKS;
        int d = idx / (32 * 16);
        int rem = idx % (32 * 16);
        int k0 = (rem & 31) * 32;
        int n0 = (rem >> 5) * 32;
        int c = t & 31, r0 = t >> 5;
        const float* srcp = (k0 < DIN) ? (Wl + (size_t)d * DIN * DOUT)
                                       : (Wr + (size_t)d * DIN * DOUT - (size_t)DIN * DOUT);
        for (int rr = 0; rr < 4; ++rr) {
            int r = r0 + rr * 8;
            tile[r][c] = srcp[(size_t)(k0 + r) * DOUT + n0 + c];
        }
        __syncthreads();
        for (int rr = 0; rr < 4; ++rr) {
            int r = r0 + rr * 8;
            Wt[((size_t)d * DOUT + n0 + r) * KDIM + k0 + c] = f2bf(tile[c][r]);
        }
        return;
    }
    // bucketing: two-phase LDS counting sort
    __shared__ int lhist[NBUCKET];
    __shared__ int lbase[NBUCKET];
    if (t < NBUCKET) lhist[t] = 0;
    __syncthreads();
    int v = (b - CAST_BLOCKS - WT_BLOCKS) * 256 + t;
    int d = -1, slot = 0;
    if (v < N_NODES) {
        d = min(cursor[v], NBUCKET - 1);
        slot = atomicAdd(&lhist[d], 1);
    }
    __syncthreads();
    if (t < NBUCKET && lhist[t] > 0) lbase[t] = atomicAdd(&bucket_cnt[t], lhist[t]);
    __syncthreads();
    if (v < N_NODES) bucket_nodes[d * N_NODES + lbase[d] + slot] = v;
}

// ---------- h = sum of neighbor bf16 rows (one wave per node) ----------
__global__ __launch_bounds__(256)
void k_build_x(const int* __restrict__ eidx2, const int* __restrict__ cursor,
               unsigned short* __restrict__ X) {
    int n = blockIdx.x * 4 + (threadIdx.x >> 6);
    int lane = threadIdx.x & 63;
    int col = lane * 8;
    int e = min(cursor[n], CAP);
    int av = eidx2[(size_t)n * CAP + lane];   // lane l holds adj[l] (garbage for l>=e, unused)
    float acc[8] = {0,0,0,0,0,0,0,0};
    int i = 0;
    for (; i + 7 < e; i += 8) {
        uint4 p[8];
#pragma unroll
        for (int j = 0; j < 8; ++j) {
            int u = __shfl(av, i + j, 64);
            p[j] = *(const uint4*)(X + (size_t)u * KDIM + DIN + col);
        }
#pragma unroll
        for (int j = 0; j < 8; ++j) {
            acc[0] += bflo(p[j].x); acc[1] += bfhi(p[j].x);
            acc[2] += bflo(p[j].y); acc[3] += bfhi(p[j].y);
            acc[4] += bflo(p[j].z); acc[5] += bfhi(p[j].z);
            acc[6] += bflo(p[j].w); acc[7] += bfhi(p[j].w);
        }
    }
    if (i + 3 < e) {
        uint4 p[4];
#pragma unroll
        for (int j = 0; j < 4; ++j) {
            int u = __shfl(av, i + j, 64);
            p[j] = *(const uint4*)(X + (size_t)u * KDIM + DIN + col);
        }
#pragma unroll
        for (int j = 0; j < 4; ++j) {
            acc[0] += bflo(p[j].x); acc[1] += bfhi(p[j].x);
            acc[2] += bflo(p[j].y); acc[3] += bfhi(p[j].y);
            acc[4] += bflo(p[j].z); acc[5] += bfhi(p[j].z);
            acc[6] += bflo(p[j].w); acc[7] += bfhi(p[j].w);
        }
        i += 4;
    }
    for (; i < e; ++i) {
        int u = __shfl(av, i, 64);
        uint4 p = *(const uint4*)(X + (size_t)u * KDIM + DIN + col);
        acc[0] += bflo(p.x); acc[1] += bfhi(p.x); acc[2] += bflo(p.y); acc[3] += bfhi(p.y);
        acc[4] += bflo(p.z); acc[5] += bfhi(p.z); acc[6] += bflo(p.w); acc[7] += bfhi(p.w);
    }
    uint4 o;
    o.x = packbf(acc[0], acc[1]); o.y = packbf(acc[2], acc[3]);
    o.z = packbf(acc[4], acc[5]); o.w = packbf(acc[6], acc[7]);
    *(uint4*)(X + (size_t)n * KDIM + col) = o;
}

// ---------- bucketed MFMA GEMM, 128x64 tile, BK=64, swizzled LDS ----------
// R0 mechanism verbatim (stage + __syncthreads + compute: TLP-reliant, no asm
// pipelining -- every explicit-pipeline variant regressed in R1-R3). Changes:
// N-split to 64-wide tiles -> grid 1344 (5.25 blocks/CU, 2x TLP; LDS 26 KB,
// 6 blocks/CU capacity) + bijective XCD-twin mapping so the 8 n0-twins of a
// tile run on ONE XCD back-to-back and share the A-panel in its L2.
__global__ __launch_bounds__(256)
void k_gemm(const unsigned short* __restrict__ X, const unsigned short* __restrict__ Wt,
            const int* __restrict__ bucket_nodes, const int* __restrict__ bucket_cnt,
            const float* __restrict__ bl, unsigned short* __restrict__ out_pre,
            float* __restrict__ bn_sum, float* __restrict__ bn_sumsq) {
    int b = blockIdx.x;
    int tile = (b & 7) + ((b >> 6) << 3);   // T%8 + 8*(T/8)
    int n0 = ((b >> 3) & 7) * 64;
    // derive (d, m0) from tile index over 128-row tiles
    int d = -1, m0 = 0, accum = 0, cnt = 0;
    for (int bb = 0; bb < NBUCKET; ++bb) {
        int c = bucket_cnt[bb];
        int nt = (c + 127) >> 7;
        if (d < 0 && tile < accum + nt) { d = bb; m0 = (tile - accum) * 128; cnt = c; }
        accum += nt;
    }
    if (d < 0) return;

    // rows of 128B (=32 banks); slot p of row holds global k-segment p^(row&7)
    __shared__ __align__(16) unsigned short As[128 * 64];
    __shared__ __align__(16) unsigned short Bs[64 * 64];
    __shared__ int ridS[128];
    __shared__ float colsum[64], colsq[64];

    int t = threadIdx.x;
    if (t < 128) {
        int gm = m0 + t;
        ridS[t] = (gm < cnt) ? bucket_nodes[d * N_NODES + gm] : -1;
        if (t < 64) { colsum[t] = 0.f; colsq[t] = 0.f; }
    }
    __syncthreads();

    int lane = t & 63, w = t >> 6;
    // staging: thread t covers rows j*32 + (t>>3), slot t&7
    int sr = t >> 3;            // 0..31
    int s = t & 7;              // LDS slot
    int sg = s ^ (sr & 7);      // swizzled global segment (row&7 == sr&7 for all j)

    const unsigned short* gA[4];
    const unsigned short* gB[2];
    unsigned short* lA[4];
    unsigned short* lB[2];
#pragma unroll
    for (int j = 0; j < 4; ++j) {
        int row = j * 32 + sr;
        int rid = max(ridS[row], 0);
        gA[j] = X + (size_t)rid * KDIM + sg * 8;
        lA[j] = &As[row * 64 + s * 8];
    }
#pragma unroll
    for (int j = 0; j < 2; ++j) {
        int row = j * 32 + sr;
        gB[j] = Wt + ((size_t)d * DOUT + n0 + row) * KDIM + sg * 8;
        lB[j] = &Bs[row * 64 + s * 8];
    }

    int wr = w >> 1, wc = w & 1;           // 2x2 wave grid; wave owns 64x32
    int lm = lane & 15, q = lane >> 4;
    int sw = lm & 7;

    f32x4 acc[4][2];
#pragma unroll
    for (int i = 0; i < 4; ++i)
#pragma unroll
        for (int j = 0; j < 2; ++j) acc[i][j] = (f32x4){0, 0, 0, 0};

    for (int kt = 0; kt < KDIM / 64; ++kt) {
#pragma unroll
        for (int j = 0; j < 4; ++j) gload_lds16(gA[j] + kt * 64, lA[j]);
#pragma unroll
        for (int j = 0; j < 2; ++j) gload_lds16(gB[j] + kt * 64, lB[j]);
        __syncthreads();

#pragma unroll
        for (int kk = 0; kk < 2; ++kk) {
            int slot = (kk * 4 + q) ^ sw;
            bf16x8 af[4], bfr[2];
#pragma unroll
            for (int mt = 0; mt < 4; ++mt)
                af[mt] = *(bf16x8*)&As[(wr * 64 + mt * 16 + lm) * 64 + slot * 8];
#pragma unroll
            for (int nt = 0; nt < 2; ++nt)
                bfr[nt] = *(bf16x8*)&Bs[(wc * 32 + nt * 16 + lm) * 64 + slot * 8];
#pragma unroll
            for (int mt = 0; mt < 4; ++mt)
#pragma unroll
                for (int nt = 0; nt < 2; ++nt)
                    acc[mt][nt] = __builtin_amdgcn_mfma_f32_16x16x32_bf16(af[mt], bfr[nt], acc[mt][nt], 0, 0, 0);
        }
        __syncthreads();
    }

    const float* blr = bl + d * DOUT + n0;
    float vsum[2] = {0, 0}, vsq[2] = {0, 0};
#pragma unroll
    for (int mt = 0; mt < 4; ++mt) {
#pragma unroll
        for (int rr = 0; rr < 4; ++rr) {
            int row = wr * 64 + mt * 16 + q * 4 + rr;
            int grow = ridS[row];
            if (grow < 0) continue;
            unsigned short* orow = out_pre + (size_t)grow * DOUT + n0;
#pragma unroll
            for (int nt = 0; nt < 2; ++nt) {
                int col = wc * 32 + nt * 16 + lm;
                float v = acc[mt][nt][rr] + blr[col];
                orow[col] = f2bf(v);
                vsum[nt] += v; vsq[nt] += v * v;
            }
        }
    }
#pragma unroll
    for (int nt = 0; nt < 2; ++nt) {
        vsum[nt] += __shfl_xor(vsum[nt], 16, 64);
        vsum[nt] += __shfl_xor(vsum[nt], 32, 64);
        vsq[nt]  += __shfl_xor(vsq[nt], 16, 64);
        vsq[nt]  += __shfl_xor(vsq[nt], 32, 64);
    }
    if (q == 0) {
#pragma unroll
        for (int nt = 0; nt < 2; ++nt) {
            atomicAdd(&colsum[wc * 32 + nt * 16 + lm], vsum[nt]);
            atomicAdd(&colsq[wc * 32 + nt * 16 + lm], vsq[nt]);
        }
    }
    __syncthreads();
    if (t < 64) {
        atomicAdd(&bn_sum[n0 + t], colsum[t]);
        atomicAdd(&bn_sumsq[n0 + t], colsq[t]);
    }
}

// ---------- fused BN-final + segment_max + BN-apply (one wave per node) ----------
__global__ __launch_bounds__(256)
void k_max(const unsigned short* __restrict__ out_pre, const int* __restrict__ eidx2,
           const int* __restrict__ cursor, const float* __restrict__ bn_sum,
           const float* __restrict__ bn_sumsq, const float* __restrict__ gamma,
           const float* __restrict__ beta, float* __restrict__ out) {
    int n = blockIdx.x * 4 + (threadIdx.x >> 6);
    int lane = threadIdx.x & 63;
    int col = lane * 8;
    int e = min(cursor[n], CAP);
    int av = eidx2[(size_t)n * CAP + lane];
    float mx[8];
    {
        uint4 p = *(const uint4*)(out_pre + (size_t)n * DOUT + col);
        mx[0] = bflo(p.x); mx[1] = bfhi(p.x); mx[2] = bflo(p.y); mx[3] = bfhi(p.y);
        mx[4] = bflo(p.z); mx[5] = bfhi(p.z); mx[6] = bflo(p.w); mx[7] = bfhi(p.w);
    }
    int i = 0;
    for (; i + 7 < e; i += 8) {
        uint4 p[8];
#pragma unroll
        for (int j = 0; j < 8; ++j) {
            int u = __shfl(av, i + j, 64);
            p[j] = *(const uint4*)(out_pre + (size_t)u * DOUT + col);
        }
#pragma unroll
        for (int j = 0; j < 8; ++j) {
            mx[0] = fmaxf(mx[0], bflo(p[j].x)); mx[1] = fmaxf(mx[1], bfhi(p[j].x));
            mx[2] = fmaxf(mx[2], bflo(p[j].y)); mx[3] = fmaxf(mx[3], bfhi(p[j].y));
            mx[4] = fmaxf(mx[4], bflo(p[j].z)); mx[5] = fmaxf(mx[5], bfhi(p[j].z));
            mx[6] = fmaxf(mx[6], bflo(p[j].w)); mx[7] = fmaxf(mx[7], bfhi(p[j].w));
        }
    }
    if (i + 3 < e) {
        uint4 p[4];
#pragma unroll
        for (int j = 0; j < 4; ++j) {
            int u = __shfl(av, i + j, 64);
            p[j] = *(const uint4*)(out_pre + (size_t)u * DOUT + col);
        }
#pragma unroll
        for (int j = 0; j < 4; ++j) {
            mx[0] = fmaxf(mx[0], bflo(p[j].x)); mx[1] = fmaxf(mx[1], bfhi(p[j].x));
            mx[2] = fmaxf(mx[2], bflo(p[j].y)); mx[3] = fmaxf(mx[3], bfhi(p[j].y));
            mx[4] = fmaxf(mx[4], bflo(p[j].z)); mx[5] = fmaxf(mx[5], bfhi(p[j].z));
            mx[6] = fmaxf(mx[6], bflo(p[j].w)); mx[7] = fmaxf(mx[7], bfhi(p[j].w));
        }
        i += 4;
    }
    for (; i < e; ++i) {
        int u = __shfl(av, i, 64);
        uint4 p = *(const uint4*)(out_pre + (size_t)u * DOUT + col);
        mx[0] = fmaxf(mx[0], bflo(p.x)); mx[1] = fmaxf(mx[1], bfhi(p.x));
        mx[2] = fmaxf(mx[2], bflo(p.y)); mx[3] = fmaxf(mx[3], bfhi(p.y));
        mx[4] = fmaxf(mx[4], bflo(p.z)); mx[5] = fmaxf(mx[5], bfhi(p.z));
        mx[6] = fmaxf(mx[6], bflo(p.w)); mx[7] = fmaxf(mx[7], bfhi(p.w));
    }
    const float inv_n = 1.0f / (float)N_NODES;
    f32x4 sm0 = *(const f32x4*)(bn_sum + col);
    f32x4 sm1 = *(const f32x4*)(bn_sum + col + 4);
    f32x4 sq0 = *(const f32x4*)(bn_sumsq + col);
    f32x4 sq1 = *(const f32x4*)(bn_sumsq + col + 4);
    f32x4 g0 = *(const f32x4*)(gamma + col);
    f32x4 g1 = *(const f32x4*)(gamma + col + 4);
    f32x4 b0 = *(const f32x4*)(beta + col);
    f32x4 b1 = *(const f32x4*)(beta + col + 4);
    f32x4 r0, r1;
#pragma unroll
    for (int jj = 0; jj < 4; ++jj) {
        float mean = sm0[jj] * inv_n;
        float var = sq0[jj] * inv_n - mean * mean;
        float sc = g0[jj] * rsqrtf(var + BN_EPS);
        r0[jj] = mx[jj] * sc + (b0[jj] - mean * sc);
    }
#pragma unroll
    for (int jj = 0; jj < 4; ++jj) {
        float mean = sm1[jj] * inv_n;
        float var = sq1[jj] * inv_n - mean * mean;
        float sc = g1[jj] * rsqrtf(var + BN_EPS);
        r1[jj] = mx[jj + 4] * sc + (b1[jj] - mean * sc);
    }
    *(f32x4*)(out + (size_t)n * DOUT + col) = r0;
    *(f32x4*)(out + (size_t)n * DOUT + col + 4) = r1;
}

extern "C" void kernel_launch(void* const* d_in, const int* in_sizes, int n_in,
                              void* d_out, int out_size, void* d_ws, size_t ws_size,
                              hipStream_t stream) {
    const float* feats = (const float*)d_in[0];
    const int*   src   = (const int*)d_in[1];
    const int*   dst   = (const int*)d_in[2];
    const float* Wl    = (const float*)d_in[3];
    const float* Wr    = (const float*)d_in[4];
    const float* bl    = (const float*)d_in[5];
    const float* gamma = (const float*)d_in[6];
    const float* beta  = (const float*)d_in[7];
    float* out = (float*)d_out;

    char* ws = (char*)d_ws;
    size_t off = 0;
    auto alloc = [&](size_t bytes) -> void* {
        off = (off + 255) & ~(size_t)255;
        void* p = ws + off;
        off += bytes;
        return p;
    };

    // zero-initialized region (contiguous & first)
    int*   cursor     = (int*)alloc(N_NODES * 4);
    int*   bucket_cnt = (int*)alloc(16 * 4);
    float* bn_sum     = (float*)alloc(DOUT * 4);
    float* bn_sumsq   = (float*)alloc(DOUT * 4);
    size_t zbytes = off;

    int* bucket_nodes = (int*)alloc((size_t)NBUCKET * N_NODES * 4);
    int* eidx2        = (int*)alloc((size_t)N_NODES * CAP * 4);
    unsigned short* X  = (unsigned short*)alloc((size_t)N_NODES * KDIM * 2);
    unsigned short* Wt = (unsigned short*)alloc((size_t)NBUCKET * DOUT * KDIM * 2);
    unsigned short* out_pre = (unsigned short*)alloc((size_t)N_NODES * DOUT * 2);

    hipMemsetAsync(d_ws, 0, zbytes, stream);

    k_scatter<<<(N_EDGES + 255) / 256, 256, 0, stream>>>(src, dst, cursor, eidx2);
    k_prep<<<CAST_BLOCKS + WT_BLOCKS + BUCKET_BLOCKS, 256, 0, stream>>>(
        feats, Wl, Wr, cursor, X, Wt, bucket_cnt, bucket_nodes);
    k_build_x<<<N_NODES / 4, 256, 0, stream>>>(eidx2, cursor, X);
    k_gemm<<<GEMM_BLOCKS, 256, 0, stream>>>(
        X, Wt, bucket_nodes, bucket_cnt, bl, out_pre, bn_sum, bn_sumsq);
    k_max<<<N_NODES / 4, 256, 0, stream>>>(out_pre, eidx2, cursor, bn_sum, bn_sumsq, gamma, beta, out);
}